// Round 4
// baseline (1763.565 us; speedup 1.0000x reference)
//
#include <hip/hip_runtime.h>

// SubsetGFlowNetTB: 17-step GFlowNet trajectory-balance forward.
// State (sel_mask, k, step) depends only on `actions`, so layer-1 is an
// incremental running sum of W1 rows; layers 2/3 are bf16 MFMA GEMMs.
// R4: operand-SWAPPED MFMA (D'[col][sample]) makes softmax lane-local
// (1 shuffle vs 80), phase C split into 2 passes (32 AGPR peak) so
// launch_bounds(512,4) fits 128 total regs -> 2 blocks/CU. Wh pre-scaled by
// log2e (exp2 directly), bh folded into ebh=exp(bh), v_cvt_pk_bf16_f32 packs.

#define NEG_INF (-1000000000.0f)
#define LOG2E 1.4426950408889634f
#define LN2   0.6931471805599453f

typedef short bf16x8 __attribute__((ext_vector_type(8)));
typedef float f32x16 __attribute__((ext_vector_type(16)));

__device__ __forceinline__ unsigned short f2bf(float x){
  unsigned int u = __float_as_uint(x);
  u = (u + 0x7FFFu + ((u >> 16) & 1u)) >> 16;   // RNE
  return (unsigned short)u;
}
__device__ __forceinline__ float bf2f(unsigned short h){
  return __uint_as_float(((unsigned int)h) << 16);
}
__device__ __forceinline__ unsigned int cvt_pk_bf16(float lo, float hi){
  unsigned int r;
  asm("v_cvt_pk_bf16_f32 %0, %1, %2" : "=v"(r) : "v"(lo), "v"(hi));
  return r;
}

// ---------------------------------------------------------------------------
// Prep: W2 (256x256 f32), Wh (256x513 f32) -> bf16 MFMA fragments.
// Fragment: lane l of tile (kt,ntg) holds M[kt*16+(l>>5)*8+i][ntg*32+(l&31)].
// whf is PRE-SCALED by log2(e) so phase C can use v_exp2 directly.
// ---------------------------------------------------------------------------
__global__ void prep_kernel(const float* __restrict__ W2, const float* __restrict__ Wh,
                            unsigned short* __restrict__ w2f, unsigned short* __restrict__ whf,
                            float* __restrict__ whstop){
  int id = blockIdx.x * 256 + threadIdx.x;
  if (id < 8192){                       // W2 fragments
    int lane = id & 63; int tile = id >> 6;   // tile = kt*8 + ntg
    int ntg = tile & 7, kt = tile >> 3;
    int col = ntg * 32 + (lane & 31);
    int k0  = kt * 16 + (lane >> 5) * 8;
    unsigned int u[4];
#pragma unroll
    for (int p = 0; p < 4; ++p){
      unsigned short lo = f2bf(W2[(k0 + 2*p    ) * 256 + col]);
      unsigned short hi = f2bf(W2[(k0 + 2*p + 1) * 256 + col]);
      u[p] = (unsigned int)lo | ((unsigned int)hi << 16);
    }
    *(uint4*)(w2f + (size_t)id * 8) = make_uint4(u[0], u[1], u[2], u[3]);
  } else if (id < 24576){               // Wh fragments (asset cols 0..511), x log2e
    int id2 = id - 8192;
    int lane = id2 & 63; int tile = id2 >> 6; // tile = kt*16 + ntg
    int ntg = tile & 15, kt = tile >> 4;
    int col = ntg * 32 + (lane & 31);
    int k0  = kt * 16 + (lane >> 5) * 8;
    unsigned int u[4];
#pragma unroll
    for (int p = 0; p < 4; ++p){
      unsigned short lo = f2bf(Wh[(k0 + 2*p    ) * 513 + col] * LOG2E);
      unsigned short hi = f2bf(Wh[(k0 + 2*p + 1) * 513 + col] * LOG2E);
      u[p] = (unsigned int)lo | ((unsigned int)hi << 16);
    }
    *(uint4*)(whf + (size_t)id2 * 8) = make_uint4(u[0], u[1], u[2], u[3]);
  } else if (id < 24832){               // stop column, f32, unscaled
    int k = id - 24576;
    whstop[k] = Wh[k * 513 + 512];
  }
}

// ---------------------------------------------------------------------------
// Fused kernel: 512 threads (8 waves) own 64 samples, loop 17 steps.
// h LDS tile [64][256] bf16 (h1 then h2), byte-XOR swizzle ((row&15)<<4).
// ---------------------------------------------------------------------------
__launch_bounds__(512, 4)
__global__ void gfn_kernel(const int* __restrict__ actions, const float* __restrict__ rp,
                           const float* __restrict__ W1, const float* __restrict__ b1,
                           const float* __restrict__ b2, const float* __restrict__ bh,
                           const unsigned short* __restrict__ w2f,
                           const unsigned short* __restrict__ whf,
                           const float* __restrict__ whstop,
                           float* __restrict__ out)
{
  __shared__ alignas(16) unsigned short h[64 * 256];    // 32 KB (h1 then h2)
  __shared__ alignas(16) float c_lds[1024];   // W1 rows 512..514 + b1
  __shared__ alignas(16) float b2t[256];      // b2 in D'-frag order [wave][lg2][r]
  __shared__ alignas(16) float ebh_t[512];    // exp(bh) [w4][pass][lg2][r][j]
  __shared__ float bh_s[513];
  __shared__ unsigned long long selw[64][9];  // pad 9: 2-way banks (free)
  __shared__ float pred_s[64][5];             // pad 5: conflict-free
  __shared__ float stopl[64];
  __shared__ float chosen[64];
  __shared__ float logpf_s[64];
  __shared__ float rp_s[64];
  __shared__ int   kcnt[64];
  __shared__ int   meta_s[64];     // arow | (full<<15) for CURRENT step
  __shared__ int   isnew_s[64];
  __shared__ int   act_s[64 * 17];

  const int tid  = threadIdx.x;
  const int wave = tid >> 6;
  const int lane = tid & 63;
  const int ln5  = lane & 31;
  const int lg2  = lane >> 5;
  const int w4   = wave & 3;            // col-group (128 cols) in phase C
  const int sg   = wave >> 2;           // sample-group (32 samples) in phase C
  const int smp  = sg * 32 + ln5;       // this lane's sample in phase C
  const int base = blockIdx.x * 64;

  // ---- init ----
  for (int i = tid; i < 1024; i += 512){
    int rrow = i >> 8, f = i & 255;
    c_lds[i] = (rrow < 3) ? W1[(512 + rrow) * 256 + f] : b1[f];
  }
  for (int i = tid; i < 513; i += 512) bh_s[i] = bh[i];
  for (int i = tid; i < 576; i += 512) ((unsigned long long*)selw)[i] = 0ULL;
  for (int i = tid; i < 64 * 17; i += 512) act_s[i] = actions[base * 17 + i];
  __syncthreads();    // bh_s ready for ebh build, act_s for meta
  if (tid < 256){
    int wv = tid >> 5, l2 = (tid >> 4) & 1, r = tid & 15;
    b2t[tid] = b2[wv * 32 + (r & 3) + 8 * (r >> 2) + 4 * l2];
  }
  {
    int wi = tid >> 7, pi = (tid >> 6) & 1, l2 = (tid >> 5) & 1, r = (tid >> 1) & 15, j = tid & 1;
    int col = wi * 128 + pi * 64 + j * 32 + (r & 3) + 8 * (r >> 2) + 4 * l2;
    ebh_t[tid] = __expf(bh_s[col]);
  }
  if (tid < 64){
    kcnt[tid] = 0; logpf_s[tid] = 0.f; rp_s[tid] = rp[base + tid];
    int a0 = act_s[tid * 17];
    meta_s[tid] = (a0 < 0) ? 0x7FFF : a0;
  }
  float S[32];
#pragma unroll
  for (int j = 0; j < 32; ++j) S[j] = 0.f;
  __syncthreads();

  char* hb = (char*)h;

  for (int t = 0; t < 17; ++t){
    // ---- Phase A: h1 = relu(x@W1+b1). thread = (feats lane*4.., samples wave*8..)
    {
      const float4 ck4 = *(const float4*)&c_lds[lane * 4];
      const float4 ct4 = *(const float4*)&c_lds[256 + lane * 4];
      const float4 cr4 = *(const float4*)&c_lds[512 + lane * 4];
      const float4 cb4 = *(const float4*)&c_lds[768 + lane * 4];
      float tf = (float)t;
      float cb0 = cb4.x + tf * ct4.x, cb1 = cb4.y + tf * ct4.y;
      float cb2 = cb4.z + tf * ct4.z, cb3 = cb4.w + tf * ct4.w;
#pragma unroll
      for (int s8 = 0; s8 < 8; ++s8){
        int s = wave * 8 + s8;
        float kf = (float)kcnt[s];
        float rv = rp_s[s];
        float v0 = fmaxf(S[s8*4+0] + kf * ck4.x + rv * cr4.x + cb0, 0.f);
        float v1 = fmaxf(S[s8*4+1] + kf * ck4.y + rv * cr4.y + cb1, 0.f);
        float v2 = fmaxf(S[s8*4+2] + kf * ck4.z + rv * cr4.z + cb2, 0.f);
        float v3 = fmaxf(S[s8*4+3] + kf * ck4.w + rv * cr4.w + cb3, 0.f);
        unsigned int u0 = cvt_pk_bf16(v0, v1);
        unsigned int u1 = cvt_pk_bf16(v2, v3);
        int byte = (s * 512 + lane * 8) ^ ((s & 15) << 4);
        *(uint2*)(hb + byte) = make_uint2(u0, u1);
      }
    }
    __syncthreads();

    // ---- Phase B (swapped): D'[feat][sample] = W2^T-frag x h1-frag ----
    {
      f32x16 aB0, aB1;
#pragma unroll
      for (int i = 0; i < 16; ++i){ aB0[i] = 0.f; aB1[i] = 0.f; }
#pragma unroll 4
      for (int kt = 0; kt < 16; ++kt){
        int off = kt * 32 + lg2 * 16;
        int r0 = ln5, r1 = 32 + ln5;
        bf16x8 s0f = *(const bf16x8*)(hb + ((r0 * 512 + off) ^ ((r0 & 15) << 4)));
        bf16x8 s1f = *(const bf16x8*)(hb + ((r1 * 512 + off) ^ ((r1 & 15) << 4)));
        bf16x8 wf  = *(const bf16x8*)(w2f + ((size_t)((kt * 8 + wave) * 64 + lane)) * 8);
        aB0 = __builtin_amdgcn_mfma_f32_32x32x16_bf16(wf, s0f, aB0, 0, 0, 0);
        aB1 = __builtin_amdgcn_mfma_f32_32x32x16_bf16(wf, s1f, aB1, 0, 0, 0);
      }
      __syncthreads();   // all h1 reads done before overwriting with h2
      // epilogue: relu + pack 4 consecutive feats -> one b64 write per (g,sg)
#pragma unroll
      for (int g = 0; g < 4; ++g){
        float4 bb = *(const float4*)&b2t[wave * 32 + lg2 * 16 + g * 4];
        int feat0 = wave * 32 + g * 8 + lg2 * 4;
        {
          float v0 = fmaxf(aB0[g*4+0] + bb.x, 0.f);
          float v1 = fmaxf(aB0[g*4+1] + bb.y, 0.f);
          float v2 = fmaxf(aB0[g*4+2] + bb.z, 0.f);
          float v3 = fmaxf(aB0[g*4+3] + bb.w, 0.f);
          int byte = (ln5 * 512 + feat0 * 2) ^ ((ln5 & 15) << 4);
          *(uint2*)(hb + byte) = make_uint2(cvt_pk_bf16(v0, v1), cvt_pk_bf16(v2, v3));
        }
        {
          int s = 32 + ln5;
          float v0 = fmaxf(aB1[g*4+0] + bb.x, 0.f);
          float v1 = fmaxf(aB1[g*4+1] + bb.y, 0.f);
          float v2 = fmaxf(aB1[g*4+2] + bb.z, 0.f);
          float v3 = fmaxf(aB1[g*4+3] + bb.w, 0.f);
          int byte = (s * 512 + feat0 * 2) ^ ((s & 15) << 4);
          *(uint2*)(hb + byte) = make_uint2(cvt_pk_bf16(v0, v1), cvt_pk_bf16(v2, v3));
        }
      }
    }
    __syncthreads();

    // ---- stop logit (col 512): 8 threads/sample ----
    {
      int s = tid >> 3, f8 = tid & 7;
      float sp = 0.f;
#pragma unroll
      for (int c = 0; c < 4; ++c){
        int byte = (s * 512 + c * 128 + f8 * 16) ^ ((s & 15) << 4);
        uint4 q = *(const uint4*)(hb + byte);
        unsigned int qq[4] = {q.x, q.y, q.z, q.w};
#pragma unroll
        for (int p = 0; p < 4; ++p){
          int f = c * 64 + f8 * 8 + 2 * p;
          sp += bf2f((unsigned short)(qq[p] & 0xFFFFu)) * whstop[f]
              + bf2f((unsigned short)(qq[p] >> 16))     * whstop[f + 1];
        }
      }
      sp += __shfl_xor(sp, 1);
      sp += __shfl_xor(sp, 2);
      sp += __shfl_xor(sp, 4);
      if (f8 == 0){
        float v = sp + bh_s[512];
        if (kcnt[s] == 0) v = NEG_INF;   // mask_stop: k>0 required
        stopl[s] = v;
      }
    }

    // ---- Phase C (swapped): lane owns sample smp, cols [w4*128,+128), 2 passes
    {
      int meta = meta_s[smp];
      int arow = meta & 0x7FFF;
      unsigned long long sw0 = selw[smp][w4 * 2];
      unsigned long long sw1 = selw[smp][w4 * 2 + 1];
      if (meta & 0x8000){ sw0 = ~0ULL; sw1 = ~0ULL; }   // full: mask all assets
      int  jl   = (arow >> 5) & 1;
      bool gw   = (arow < 512) && ((arow >> 7) == w4) && (((arow >> 2) & 1) == lg2);
      int  rtar = (arow & 3) | (((arow >> 3) & 3) << 2);
      float sum = 0.f;

#pragma unroll
      for (int p = 0; p < 2; ++p){
        f32x16 a0, a1;
#pragma unroll
        for (int i = 0; i < 16; ++i){ a0[i] = 0.f; a1[i] = 0.f; }
#pragma unroll 4
        for (int kt = 0; kt < 16; ++kt){
          int off = kt * 32 + lg2 * 16;
          bf16x8 bf_ = *(const bf16x8*)(hb + ((smp * 512 + off) ^ ((smp & 15) << 4)));
          const unsigned short* wk = whf + ((size_t)((kt * 16 + w4 * 4 + p * 2) * 64 + lane)) * 8;
          bf16x8 w0 = *(const bf16x8*)(wk);
          bf16x8 w1 = *(const bf16x8*)(wk + 512);
          a0 = __builtin_amdgcn_mfma_f32_32x32x16_bf16(w0, bf_, a0, 0, 0, 0);
          a1 = __builtin_amdgcn_mfma_f32_32x32x16_bf16(w1, bf_, a1, 0, 0, 0);
        }
        unsigned long long swp = p ? sw1 : sw0;
        int tr = (gw && (((arow >> 6) & 1) == p)) ? rtar : -1;
        float cval = 0.f;
        const float* ebp = &ebh_t[w4 * 128 + p * 64 + lg2 * 32];
#pragma unroll
        for (int r = 0; r < 16; r += 2){
          float4 eb = *(const float4*)&ebp[r * 2];
          {
            int rf = (r & 3) + 8 * (r >> 2) + 4 * lg2;
            unsigned long long tt = swp >> rf;
            float v0 = ((unsigned)tt & 1u)         ? NEG_INF : a0[r];
            float v1 = ((unsigned)(tt >> 32) & 1u) ? NEG_INF : a1[r];
            sum = fmaf(__builtin_amdgcn_exp2f(v0), eb.x, sum);
            sum = fmaf(__builtin_amdgcn_exp2f(v1), eb.y, sum);
            float cand = jl ? a1[r] : a0[r];
            cval = (r == tr) ? cand : cval;
          }
          {
            int r2 = r + 1;
            int rf = (r2 & 3) + 8 * (r2 >> 2) + 4 * lg2;
            unsigned long long tt = swp >> rf;
            float v0 = ((unsigned)tt & 1u)         ? NEG_INF : a0[r2];
            float v1 = ((unsigned)(tt >> 32) & 1u) ? NEG_INF : a1[r2];
            sum = fmaf(__builtin_amdgcn_exp2f(v0), eb.z, sum);
            sum = fmaf(__builtin_amdgcn_exp2f(v1), eb.w, sum);
            float cand = jl ? a1[r2] : a0[r2];
            cval = (r2 == tr) ? cand : cval;
          }
        }
        if (tr >= 0){
          bool mb = (swp >> (arow & 63)) & 1ULL;
          chosen[smp] = mb ? NEG_INF : fmaf(cval, LN2, bh_s[arow]);
        }
      } // passes
      sum += __shfl_xor(sum, 32);
      if (lg2 == 0) pred_s[smp][w4] = sum;
    }
    __syncthreads();

    // ---- finalize: lse, logpf, state update, next-step meta ----
    if (tid < 64){
      int row = tid;
      float tot = __expf(stopl[row])
                + pred_s[row][0] + pred_s[row][1] + pred_s[row][2] + pred_s[row][3];
      float lse = __logf(tot);
      int a = act_s[row * 17 + t];
      if (a >= 0){
        float cv = (a >= 512) ? stopl[row] : chosen[row];
        logpf_s[row] += cv - lse;
      }
      int k = kcnt[row];
      int isn = 0;
      if (a >= 0 && a < 512){
        unsigned long long old = selw[row][a >> 6];
        if (!((old >> (a & 63)) & 1ULL)){
          isn = 1;
          selw[row][a >> 6] = old | (1ULL << (a & 63));
          k = k + 1;
          kcnt[row] = k;
        }
      }
      isnew_s[row] = isn;
      if (t < 16){
        int a2 = act_s[row * 17 + t + 1];
        meta_s[row] = ((a2 < 0) ? 0x7FFF : a2) | ((k >= 16) ? 0x8000 : 0);
      }
    }
    __syncthreads();

    // ---- layer-1 running-sum update: S += W1[a, lane*4..+4) if new ----
#pragma unroll
    for (int s8 = 0; s8 < 8; ++s8){
      int s = wave * 8 + s8;
      if (isnew_s[s]){
        int a = act_s[s * 17 + t];
        float4 v = *(const float4*)(W1 + (size_t)a * 256 + lane * 4);
        S[s8*4+0] += v.x; S[s8*4+1] += v.y; S[s8*4+2] += v.z; S[s8*4+3] += v.w;
      }
    }
  } // step loop

  if (tid < 64) out[base + tid] = logpf_s[tid];
}

extern "C" void kernel_launch(void* const* d_in, const int* in_sizes, int n_in,
                              void* d_out, int out_size, void* d_ws, size_t ws_size,
                              hipStream_t stream)
{
  const int*   actions = (const int*)d_in[0];
  const float* rp  = (const float*)d_in[1];
  const float* W1  = (const float*)d_in[2];
  const float* b1  = (const float*)d_in[3];
  const float* W2  = (const float*)d_in[4];
  const float* b2  = (const float*)d_in[5];
  const float* Wh  = (const float*)d_in[6];
  const float* bh  = (const float*)d_in[7];
  float* out = (float*)d_out;

  unsigned short* w2f = (unsigned short*)d_ws;          // 65536  bf16 (128 KB)
  unsigned short* whf = w2f + 65536;                    // 131072 bf16 (256 KB)
  float* whstop = (float*)(whf + 131072);               // 256 f32

  prep_kernel<<<97, 256, 0, stream>>>(W2, Wh, w2f, whf, whstop);
  gfn_kernel<<<1024, 512, 0, stream>>>(actions, rp, W1, b1, b2, bh, w2f, whf, whstop, out);
}

// Round 5
// 792.371 us; speedup vs baseline: 2.2257x; 2.2257x over previous
//
#include <hip/hip_runtime.h>

// SubsetGFlowNetTB: 17-step GFlowNet trajectory-balance forward.
// State (sel_mask, k, step) depends only on `actions`, so layer-1 is an
// incremental running sum of W1 rows; layers 2/3 are bf16 MFMA GEMMs.
// R5: block = 256 threads / 4 waves / 32 samples, launch_bounds(256,2).
// At ~192 unified regs/wave the HW caps at 2 waves/SIMD = 8 waves/CU; two
// independent 4-wave blocks per CU overlap each other's barrier drains
// (R2/R4 proved the 128-reg budget spills ~5GB; stay at 256-reg budget).
// Keeps R4's swapped-MFMA lane-local softmax epilogue. Stop weights in LDS.

#define NEG_INF (-1000000000.0f)
#define LOG2E 1.4426950408889634f
#define LN2   0.6931471805599453f

typedef short bf16x8 __attribute__((ext_vector_type(8)));
typedef float f32x16 __attribute__((ext_vector_type(16)));

__device__ __forceinline__ unsigned short f2bf(float x){
  unsigned int u = __float_as_uint(x);
  u = (u + 0x7FFFu + ((u >> 16) & 1u)) >> 16;   // RNE
  return (unsigned short)u;
}
__device__ __forceinline__ float bf2f(unsigned short h){
  return __uint_as_float(((unsigned int)h) << 16);
}
__device__ __forceinline__ unsigned int cvt_pk_bf16(float lo, float hi){
  unsigned int r;
  asm("v_cvt_pk_bf16_f32 %0, %1, %2" : "=v"(r) : "v"(lo), "v"(hi));
  return r;
}

// ---------------------------------------------------------------------------
// Prep: W2 (256x256 f32), Wh (256x513 f32) -> bf16 MFMA fragments.
// Fragment: lane l of tile (kt,ntg) holds M[kt*16+(l>>5)*8+i][ntg*32+(l&31)].
// whf is PRE-SCALED by log2(e) so phase C can use v_exp2 directly.
// ---------------------------------------------------------------------------
__global__ void prep_kernel(const float* __restrict__ W2, const float* __restrict__ Wh,
                            unsigned short* __restrict__ w2f, unsigned short* __restrict__ whf,
                            float* __restrict__ whstop){
  int id = blockIdx.x * 256 + threadIdx.x;
  if (id < 8192){                       // W2 fragments
    int lane = id & 63; int tile = id >> 6;   // tile = kt*8 + ntg
    int ntg = tile & 7, kt = tile >> 3;
    int col = ntg * 32 + (lane & 31);
    int k0  = kt * 16 + (lane >> 5) * 8;
    unsigned int u[4];
#pragma unroll
    for (int p = 0; p < 4; ++p){
      unsigned short lo = f2bf(W2[(k0 + 2*p    ) * 256 + col]);
      unsigned short hi = f2bf(W2[(k0 + 2*p + 1) * 256 + col]);
      u[p] = (unsigned int)lo | ((unsigned int)hi << 16);
    }
    *(uint4*)(w2f + (size_t)id * 8) = make_uint4(u[0], u[1], u[2], u[3]);
  } else if (id < 24576){               // Wh fragments (asset cols 0..511), x log2e
    int id2 = id - 8192;
    int lane = id2 & 63; int tile = id2 >> 6; // tile = kt*16 + ntg
    int ntg = tile & 15, kt = tile >> 4;
    int col = ntg * 32 + (lane & 31);
    int k0  = kt * 16 + (lane >> 5) * 8;
    unsigned int u[4];
#pragma unroll
    for (int p = 0; p < 4; ++p){
      unsigned short lo = f2bf(Wh[(k0 + 2*p    ) * 513 + col] * LOG2E);
      unsigned short hi = f2bf(Wh[(k0 + 2*p + 1) * 513 + col] * LOG2E);
      u[p] = (unsigned int)lo | ((unsigned int)hi << 16);
    }
    *(uint4*)(whf + (size_t)id2 * 8) = make_uint4(u[0], u[1], u[2], u[3]);
  } else if (id < 24832){               // stop column, f32, unscaled
    int k = id - 24576;
    whstop[k] = Wh[k * 513 + 512];
  }
}

// ---------------------------------------------------------------------------
// Fused kernel: 256 threads (4 waves) own 32 samples, loop 17 steps.
// h LDS tile [32][256] bf16 (h1 then h2), byte-XOR swizzle ((row&15)<<4).
// ---------------------------------------------------------------------------
__launch_bounds__(256, 2)
__global__ void gfn_kernel(const int* __restrict__ actions, const float* __restrict__ rp,
                           const float* __restrict__ W1, const float* __restrict__ b1,
                           const float* __restrict__ b2, const float* __restrict__ bh,
                           const unsigned short* __restrict__ w2f,
                           const unsigned short* __restrict__ whf,
                           const float* __restrict__ whstop,
                           float* __restrict__ out)
{
  __shared__ alignas(16) unsigned short h[32 * 256];    // 16 KB (h1 then h2)
  __shared__ alignas(16) float c_lds[1024];   // W1 rows 512..514 + b1
  __shared__ alignas(16) float b2t[256];      // b2 in D'-frag order
  __shared__ alignas(16) float ebh_t[512];    // exp(bh) [wave][pass][lg2][r][j]
  __shared__ float bh_s[513];
  __shared__ float whst_s[256];               // Wh stop column
  __shared__ unsigned long long selw[32][9];  // pad 9: 2-way banks (free)
  __shared__ float pred_s[32][5];             // pad 5: conflict-free
  __shared__ float stopl[32];
  __shared__ float chosen[32];
  __shared__ float logpf_s[32];
  __shared__ float rp_s[32];
  __shared__ int   kcnt[32];
  __shared__ int   meta_s[32];     // arow | (full<<15) for CURRENT step
  __shared__ int   isnew_s[32];
  __shared__ int   act_s[32 * 17];

  const int tid  = threadIdx.x;
  const int wave = tid >> 6;            // 0..3
  const int lane = tid & 63;
  const int ln5  = lane & 31;
  const int lg2  = lane >> 5;
  const int base = blockIdx.x * 32;

  // ---- init ----
  for (int i = tid; i < 1024; i += 256){
    int rrow = i >> 8, f = i & 255;
    c_lds[i] = (rrow < 3) ? W1[(512 + rrow) * 256 + f] : b1[f];
  }
  for (int i = tid; i < 513; i += 256) bh_s[i] = bh[i];
  whst_s[tid] = whstop[tid];
  for (int i = tid; i < 288; i += 256) ((unsigned long long*)selw)[i] = 0ULL;
  for (int i = tid; i < 544; i += 256) act_s[i] = actions[base * 17 + i];
  __syncthreads();    // bh_s ready for ebh build, act_s for meta
  {
    int wv = tid >> 6, ti = (tid >> 5) & 1, l2 = (tid >> 4) & 1, r = tid & 15;
    b2t[tid] = b2[wv * 64 + ti * 32 + (r & 3) + 8 * (r >> 2) + 4 * l2];
  }
  for (int i = tid; i < 512; i += 256){
    int wi = i >> 7, pi = (i >> 6) & 1, l2 = (i >> 5) & 1, r = (i >> 1) & 15, j = i & 1;
    int col = wi * 128 + pi * 64 + j * 32 + (r & 3) + 8 * (r >> 2) + 4 * l2;
    ebh_t[i] = __expf(bh_s[col]);
  }
  if (tid < 32){
    kcnt[tid] = 0; logpf_s[tid] = 0.f; rp_s[tid] = rp[base + tid];
    int a0 = act_s[tid * 17];
    meta_s[tid] = (a0 < 0) ? 0x7FFF : a0;
  }
  float S[32];
#pragma unroll
  for (int j = 0; j < 32; ++j) S[j] = 0.f;
  __syncthreads();

  char* hb = (char*)h;

  for (int t = 0; t < 17; ++t){
    // ---- Phase A: h1 = relu(x@W1+b1). thread = (feats lane*4.., samples wave*8..)
    {
      const float4 ck4 = *(const float4*)&c_lds[lane * 4];
      const float4 ct4 = *(const float4*)&c_lds[256 + lane * 4];
      const float4 cr4 = *(const float4*)&c_lds[512 + lane * 4];
      const float4 cb4 = *(const float4*)&c_lds[768 + lane * 4];
      float tf = (float)t;
      float cb0 = cb4.x + tf * ct4.x, cb1 = cb4.y + tf * ct4.y;
      float cb2 = cb4.z + tf * ct4.z, cb3 = cb4.w + tf * ct4.w;
#pragma unroll
      for (int s8 = 0; s8 < 8; ++s8){
        int s = wave * 8 + s8;
        float kf = (float)kcnt[s];
        float rv = rp_s[s];
        float v0 = fmaxf(S[s8*4+0] + kf * ck4.x + rv * cr4.x + cb0, 0.f);
        float v1 = fmaxf(S[s8*4+1] + kf * ck4.y + rv * cr4.y + cb1, 0.f);
        float v2 = fmaxf(S[s8*4+2] + kf * ck4.z + rv * cr4.z + cb2, 0.f);
        float v3 = fmaxf(S[s8*4+3] + kf * ck4.w + rv * cr4.w + cb3, 0.f);
        unsigned int u0 = cvt_pk_bf16(v0, v1);
        unsigned int u1 = cvt_pk_bf16(v2, v3);
        int byte = (s * 512 + lane * 8) ^ ((s & 15) << 4);
        *(uint2*)(hb + byte) = make_uint2(u0, u1);
      }
    }
    __syncthreads();

    // ---- Phase B (swapped): D'[feat][sample] = W2^T-frag x h1-frag ----
    // wave owns feats [wave*64, +64) = tiles ntg = wave*2, wave*2+1
    {
      f32x16 aB0, aB1;
#pragma unroll
      for (int i = 0; i < 16; ++i){ aB0[i] = 0.f; aB1[i] = 0.f; }
#pragma unroll 4
      for (int kt = 0; kt < 16; ++kt){
        int off = kt * 32 + lg2 * 16;
        bf16x8 sf = *(const bf16x8*)(hb + ((ln5 * 512 + off) ^ ((ln5 & 15) << 4)));
        bf16x8 w0 = *(const bf16x8*)(w2f + ((size_t)((kt * 8 + wave * 2    ) * 64 + lane)) * 8);
        bf16x8 w1 = *(const bf16x8*)(w2f + ((size_t)((kt * 8 + wave * 2 + 1) * 64 + lane)) * 8);
        aB0 = __builtin_amdgcn_mfma_f32_32x32x16_bf16(w0, sf, aB0, 0, 0, 0);
        aB1 = __builtin_amdgcn_mfma_f32_32x32x16_bf16(w1, sf, aB1, 0, 0, 0);
      }
      __syncthreads();   // all h1 reads done before overwriting with h2
      // epilogue: relu + pack 4 consecutive feats -> one b64 write per (g,tile)
#pragma unroll
      for (int g = 0; g < 4; ++g){
        float4 bb0 = *(const float4*)&b2t[wave * 64      + lg2 * 16 + g * 4];
        float4 bb1 = *(const float4*)&b2t[wave * 64 + 32 + lg2 * 16 + g * 4];
        int feat0 = wave * 64 + g * 8 + lg2 * 4;
        {
          float v0 = fmaxf(aB0[g*4+0] + bb0.x, 0.f);
          float v1 = fmaxf(aB0[g*4+1] + bb0.y, 0.f);
          float v2 = fmaxf(aB0[g*4+2] + bb0.z, 0.f);
          float v3 = fmaxf(aB0[g*4+3] + bb0.w, 0.f);
          int byte = (ln5 * 512 + feat0 * 2) ^ ((ln5 & 15) << 4);
          *(uint2*)(hb + byte) = make_uint2(cvt_pk_bf16(v0, v1), cvt_pk_bf16(v2, v3));
        }
        {
          float v0 = fmaxf(aB1[g*4+0] + bb1.x, 0.f);
          float v1 = fmaxf(aB1[g*4+1] + bb1.y, 0.f);
          float v2 = fmaxf(aB1[g*4+2] + bb1.z, 0.f);
          float v3 = fmaxf(aB1[g*4+3] + bb1.w, 0.f);
          int byte = (ln5 * 512 + (feat0 + 32) * 2) ^ ((ln5 & 15) << 4);
          *(uint2*)(hb + byte) = make_uint2(cvt_pk_bf16(v0, v1), cvt_pk_bf16(v2, v3));
        }
      }
    }
    __syncthreads();

    // ---- stop logit (col 512): 8 threads/sample ----
    {
      int s = tid >> 3, f8 = tid & 7;
      float sp = 0.f;
#pragma unroll
      for (int c = 0; c < 4; ++c){
        int byte = (s * 512 + c * 128 + f8 * 16) ^ ((s & 15) << 4);
        uint4 q = *(const uint4*)(hb + byte);
        unsigned int qq[4] = {q.x, q.y, q.z, q.w};
#pragma unroll
        for (int p = 0; p < 4; ++p){
          int f = c * 64 + f8 * 8 + 2 * p;
          sp += bf2f((unsigned short)(qq[p] & 0xFFFFu)) * whst_s[f]
              + bf2f((unsigned short)(qq[p] >> 16))     * whst_s[f + 1];
        }
      }
      sp += __shfl_xor(sp, 1);
      sp += __shfl_xor(sp, 2);
      sp += __shfl_xor(sp, 4);
      if (f8 == 0){
        float v = sp + bh_s[512];
        if (kcnt[s] == 0) v = NEG_INF;   // mask_stop: k>0 required
        stopl[s] = v;
      }
    }

    // ---- Phase C (swapped): lane owns sample ln5, cols [wave*128,+128), 2 passes
    {
      int meta = meta_s[ln5];
      int arow = meta & 0x7FFF;
      unsigned long long sw0 = selw[ln5][wave * 2];
      unsigned long long sw1 = selw[ln5][wave * 2 + 1];
      if (meta & 0x8000){ sw0 = ~0ULL; sw1 = ~0ULL; }   // full: mask all assets
      int  jl   = (arow >> 5) & 1;
      bool gw   = (arow < 512) && ((arow >> 7) == wave) && (((arow >> 2) & 1) == lg2);
      int  rtar = (arow & 3) | (((arow >> 3) & 3) << 2);
      float sum = 0.f;

#pragma unroll
      for (int p = 0; p < 2; ++p){
        f32x16 a0, a1;
#pragma unroll
        for (int i = 0; i < 16; ++i){ a0[i] = 0.f; a1[i] = 0.f; }
#pragma unroll 4
        for (int kt = 0; kt < 16; ++kt){
          int off = kt * 32 + lg2 * 16;
          bf16x8 bf_ = *(const bf16x8*)(hb + ((ln5 * 512 + off) ^ ((ln5 & 15) << 4)));
          const unsigned short* wk = whf + ((size_t)((kt * 16 + wave * 4 + p * 2) * 64 + lane)) * 8;
          bf16x8 w0 = *(const bf16x8*)(wk);
          bf16x8 w1 = *(const bf16x8*)(wk + 512);
          a0 = __builtin_amdgcn_mfma_f32_32x32x16_bf16(w0, bf_, a0, 0, 0, 0);
          a1 = __builtin_amdgcn_mfma_f32_32x32x16_bf16(w1, bf_, a1, 0, 0, 0);
        }
        unsigned long long swp = p ? sw1 : sw0;
        int tr = (gw && (((arow >> 6) & 1) == p)) ? rtar : -1;
        float cval = 0.f;
        const float* ebp = &ebh_t[wave * 128 + p * 64 + lg2 * 32];
#pragma unroll
        for (int r = 0; r < 16; r += 2){
          float4 eb = *(const float4*)&ebp[r * 2];
          {
            int rf = (r & 3) + 8 * (r >> 2) + 4 * lg2;
            unsigned long long tt = swp >> rf;
            float v0 = ((unsigned)tt & 1u)         ? NEG_INF : a0[r];
            float v1 = ((unsigned)(tt >> 32) & 1u) ? NEG_INF : a1[r];
            sum = fmaf(__builtin_amdgcn_exp2f(v0), eb.x, sum);
            sum = fmaf(__builtin_amdgcn_exp2f(v1), eb.y, sum);
            float cand = jl ? a1[r] : a0[r];
            cval = (r == tr) ? cand : cval;
          }
          {
            int r2 = r + 1;
            int rf = (r2 & 3) + 8 * (r2 >> 2) + 4 * lg2;
            unsigned long long tt = swp >> rf;
            float v0 = ((unsigned)tt & 1u)         ? NEG_INF : a0[r2];
            float v1 = ((unsigned)(tt >> 32) & 1u) ? NEG_INF : a1[r2];
            sum = fmaf(__builtin_amdgcn_exp2f(v0), eb.z, sum);
            sum = fmaf(__builtin_amdgcn_exp2f(v1), eb.w, sum);
            float cand = jl ? a1[r2] : a0[r2];
            cval = (r2 == tr) ? cand : cval;
          }
        }
        if (tr >= 0){
          bool mb = (swp >> (arow & 63)) & 1ULL;
          chosen[ln5] = mb ? NEG_INF : fmaf(cval, LN2, bh_s[arow]);
        }
      } // passes
      sum += __shfl_xor(sum, 32);
      if (lg2 == 0) pred_s[ln5][wave] = sum;
    }
    __syncthreads();

    // ---- finalize: lse, logpf, state update, next-step meta ----
    if (tid < 32){
      int row = tid;
      float tot = __expf(stopl[row])
                + pred_s[row][0] + pred_s[row][1] + pred_s[row][2] + pred_s[row][3];
      float lse = __logf(tot);
      int a = act_s[row * 17 + t];
      if (a >= 0){
        float cv = (a >= 512) ? stopl[row] : chosen[row];
        logpf_s[row] += cv - lse;
      }
      int k = kcnt[row];
      int isn = 0;
      if (a >= 0 && a < 512){
        unsigned long long old = selw[row][a >> 6];
        if (!((old >> (a & 63)) & 1ULL)){
          isn = 1;
          selw[row][a >> 6] = old | (1ULL << (a & 63));
          k = k + 1;
          kcnt[row] = k;
        }
      }
      isnew_s[row] = isn;
      if (t < 16){
        int a2 = act_s[row * 17 + t + 1];
        meta_s[row] = ((a2 < 0) ? 0x7FFF : a2) | ((k >= 16) ? 0x8000 : 0);
      }
    }
    __syncthreads();

    // ---- layer-1 running-sum update: S += W1[a, lane*4..+4) if new ----
#pragma unroll
    for (int s8 = 0; s8 < 8; ++s8){
      int s = wave * 8 + s8;
      if (isnew_s[s]){
        int a = act_s[s * 17 + t];
        float4 v = *(const float4*)(W1 + (size_t)a * 256 + lane * 4);
        S[s8*4+0] += v.x; S[s8*4+1] += v.y; S[s8*4+2] += v.z; S[s8*4+3] += v.w;
      }
    }
  } // step loop

  if (tid < 32) out[base + tid] = logpf_s[tid];
}

extern "C" void kernel_launch(void* const* d_in, const int* in_sizes, int n_in,
                              void* d_out, int out_size, void* d_ws, size_t ws_size,
                              hipStream_t stream)
{
  const int*   actions = (const int*)d_in[0];
  const float* rp  = (const float*)d_in[1];
  const float* W1  = (const float*)d_in[2];
  const float* b1  = (const float*)d_in[3];
  const float* W2  = (const float*)d_in[4];
  const float* b2  = (const float*)d_in[5];
  const float* Wh  = (const float*)d_in[6];
  const float* bh  = (const float*)d_in[7];
  float* out = (float*)d_out;

  unsigned short* w2f = (unsigned short*)d_ws;          // 65536  bf16 (128 KB)
  unsigned short* whf = w2f + 65536;                    // 131072 bf16 (256 KB)
  float* whstop = (float*)(whf + 131072);               // 256 f32

  prep_kernel<<<97, 256, 0, stream>>>(W2, Wh, w2f, whf, whstop);
  gfn_kernel<<<2048, 256, 0, stream>>>(actions, rp, W1, b1, b2, bh, w2f, whf, whstop, out);
}